// Round 6
// baseline (235.067 us; speedup 1.0000x reference)
//
#include <hip/hip_runtime.h>

// Correlation / cost volume:
// corr[n, dy*9+dx, h, w] = sum_c f0[n,c,h,w] * f1[n,c,h+dy-4,w+dx-4] (0-padded)
// N=8, C=256, H=W=128 -> D=9, 81 disp channels.
//
// R5 bug: LDS row stride 44 < needed 136 floats -> intra-LDS corruption. Fixed.
//
// Structure (unchanged from R5 intent):
//  - dy = 3 (grid, dyg) x 3 (waves, j). Block 192 th = 3 waves; tile 4x128 px.
//  - PX=8: 16-float window serves 72 FMA (LDS bytes/FMA halved vs R4).
//  - f0 + f1 register-prefetched one chunk ahead: k-loop touches LDS+regs only.
//  - 3 waves read IDENTICAL f0 addresses -> L1 broadcasts the x3 re-read.
//  - XCD chunk swizzle: XCD x -> image x; dyg-siblings adjacent in time.
// LDS layout: logical row = 34 16B-units (u0 = lo-pad cols -4..-1, u1..32 =
// cols 0..127, u33 = hi-pad 128..131). Physical unit = u + (u>>3) (skew) ->
// row 38 units = 152 floats. Quarter-wave b128 reads (unit 2tx+i, tx=0..15)
// hit every 4-bank group exactly 2x (free per m136); unskewed would be 4-way.

#define DD    9
#define Hh    128
#define Ww    128
#define Cc    256
#define TR    4          // output rows per block
#define SR    6          // staged f1 rows (covers ty 0..3 + j 0..2)
#define RF    152        // physical row floats (38 units)
#define NCH   128        // channel chunks (2 channels each)

__device__ __forceinline__ int skewu(int u) { return u + (u >> 3); }

__global__ __launch_bounds__(192) __attribute__((amdgpu_waves_per_eu(2, 8)))
void corr_kernel(const float* __restrict__ f0,
                 const float* __restrict__ f1,
                 float* __restrict__ out) {
    const int tid = threadIdx.x;
    const int j   = tid >> 6;          // wave: dy offset 0..2
    const int ty  = (tid >> 4) & 3;    // output row within tile 0..3
    const int tx  = tid & 15;          // col group (8 px) 0..15

    const int bid  = blockIdx.x;
    const int work = (bid & 7) * 96 + (bid >> 3);   // XCD chunk swizzle
    const int n    = work / 96;
    const int rem  = work % 96;
    const int hb   = rem / 3;          // 0..31
    const int dyg  = rem % 3;
    const int dy   = dyg * 3 + j;

    __shared__ float lds[2][2][SR][RF];   // 14592 B double-buffered

    const size_t plane = (size_t)Hh * Ww;
    const int h     = hb * TR + ty;
    const int gbase = hb * TR + dyg * 3 - 4;   // first staged f1 row

    // staging: 192 threads = 6 rows x 32 16B-units
    const int sr  = tid >> 5;          // 0..5
    const int su  = tid & 31;          // covers global cols 4*su..4*su+3
    const int gsr = gbase + sr;
    const bool sok = ((unsigned)gsr < (unsigned)Hh);
    const int woff = 4 * skewu(1 + su);          // physical float offset of store

    const float* f0p = f0 + ((size_t)n * Cc) * plane + (size_t)h * Ww + 8 * tx;
    const float* f1p = f1 + ((size_t)n * Cc) * plane + (size_t)gsr * Ww + 4 * su;

    const float4 zero4 = make_float4(0.f, 0.f, 0.f, 0.f);

    // zero pad units (u=0 -> floats 0..3, u=33 -> floats 148..151) of all
    // 2*2*6 = 24 rows; 24 rows x 8 floats = 192 threads, one float each.
    {
        const int zr = tid >> 3;       // 0..23
        const int zs = tid & 7;
        ((float*)lds)[zr * RF + (zs < 4 ? zs : 144 + zs)] = 0.f;
    }

    // read offsets (physical float index of the 4 window quads), hoisted
    const int roff0 = 4 * skewu(2 * tx + 0);
    const int roff1 = 4 * skewu(2 * tx + 1);
    const int roff2 = 4 * skewu(2 * tx + 2);
    const int roff3 = 4 * skewu(2 * tx + 3);

    float4 acc[DD][2];
#pragma unroll
    for (int d = 0; d < DD; ++d) { acc[d][0] = zero4; acc[d][1] = zero4; }

    float4 a0c0, a1c0, a0c1, a1c1;     // f0 current chunk
    float4 n0c0, n1c0, n0c1, n1c1;     // f0 next chunk
    float4 s_c0, s_c1;                 // f1 staging

#define LOADF1(K)                                                        \
    {                                                                    \
        const float* p = f1p + (size_t)(2 * (K)) * plane;                \
        s_c0 = sok ? *(const float4*)(p)         : zero4;                \
        s_c1 = sok ? *(const float4*)(p + plane) : zero4;                \
    }

#define LOADF0(K, d00, d10, d01, d11)                                    \
    {                                                                    \
        const float* p = f0p + (size_t)(2 * (K)) * plane;                \
        d00 = *(const float4*)(p);                                       \
        d10 = *(const float4*)(p + 4);                                   \
        d01 = *(const float4*)(p + plane);                               \
        d11 = *(const float4*)(p + plane + 4);                           \
    }

#define STOREF1(B)                                                       \
    {                                                                    \
        *(float4*)(&lds[B][0][sr][woff]) = s_c0;                         \
        *(float4*)(&lds[B][1][sr][woff]) = s_c1;                         \
    }

#define COMPUTE(B)                                                       \
    {                                                                    \
        _Pragma("unroll")                                                \
        for (int cc = 0; cc < 2; ++cc) {                                 \
            const float* lrow = &lds[B][cc][ty + j][0];                  \
            float w[16];                                                 \
            {                                                            \
                const float4 q0 = *(const float4*)(lrow + roff0);        \
                const float4 q1 = *(const float4*)(lrow + roff1);        \
                const float4 q2 = *(const float4*)(lrow + roff2);        \
                const float4 q3 = *(const float4*)(lrow + roff3);        \
                w[0]=q0.x;  w[1]=q0.y;  w[2]=q0.z;  w[3]=q0.w;           \
                w[4]=q1.x;  w[5]=q1.y;  w[6]=q1.z;  w[7]=q1.w;           \
                w[8]=q2.x;  w[9]=q2.y;  w[10]=q2.z; w[11]=q2.w;          \
                w[12]=q3.x; w[13]=q3.y; w[14]=q3.z; w[15]=q3.w;          \
            }                                                            \
            const float4 fa = cc ? a0c1 : a0c0;                          \
            const float4 fb = cc ? a1c1 : a1c0;                          \
            _Pragma("unroll")                                            \
            for (int dx = 0; dx < DD; ++dx) {                            \
                acc[dx][0].x += fa.x * w[dx];                            \
                acc[dx][0].y += fa.y * w[dx + 1];                        \
                acc[dx][0].z += fa.z * w[dx + 2];                        \
                acc[dx][0].w += fa.w * w[dx + 3];                        \
                acc[dx][1].x += fb.x * w[dx + 4];                        \
                acc[dx][1].y += fb.y * w[dx + 5];                        \
                acc[dx][1].z += fb.z * w[dx + 6];                        \
                acc[dx][1].w += fb.w * w[dx + 7];                        \
            }                                                            \
        }                                                                \
    }

    LOADF1(0);
    LOADF0(0, a0c0, a1c0, a0c1, a1c1);
    STOREF1(0);
    __syncthreads();

#pragma unroll 2
    for (int k = 0; k < NCH; ++k) {
        const int b = k & 1;
        if (k + 1 < NCH) {
            LOADF1(k + 1);
            LOADF0(k + 1, n0c0, n1c0, n0c1, n1c1);
        }
        COMPUTE(b);
        if (k + 1 < NCH) {
            STOREF1(b ^ 1);            // buffer nobody reads this iteration
            a0c0 = n0c0; a1c0 = n1c0; a0c1 = n0c1; a1c1 = n1c1;
            __syncthreads();           // single barrier per iteration
        }
    }

    // epilogue: 9 dx x 2 float4 stores
    float* outp = out + ((size_t)n * (DD * DD)) * plane + (size_t)h * Ww + 8 * tx;
#pragma unroll
    for (int dx = 0; dx < DD; ++dx) {
        float* op = outp + (size_t)(dy * DD + dx) * plane;
        *(float4*)(op)     = acc[dx][0];
        *(float4*)(op + 4) = acc[dx][1];
    }
}

extern "C" void kernel_launch(void* const* d_in, const int* in_sizes, int n_in,
                              void* d_out, int out_size, void* d_ws, size_t ws_size,
                              hipStream_t stream) {
    const float* f0 = (const float*)d_in[0];
    const float* f1 = (const float*)d_in[1];
    float* out = (float*)d_out;
    // grid: 8 n * 32 hb * 3 dyg = 768 blocks, 192 threads
    corr_kernel<<<dim3(768), dim3(192), 0, stream>>>(f0, f1, out);
}

// Round 7
// 231.592 us; speedup vs baseline: 1.0150x; 1.0150x over previous
//
#include <hip/hip_runtime.h>

// Correlation / cost volume:
// corr[n, dy*9+dx, h, w] = sum_c f0[n,c,h,w] * f1[n,c,h+dy-4,w+dx-4] (0-padded)
// N=8, C=256, H=W=128 -> D=9, 81 disp channels.
//
// R4/R6 lesson: both latency-bound at <=9 waves/CU (Occ 24%/13%, VALU 29%/21%,
// no pipe saturated). R7: 18 waves/CU.
//  - block 192 th = 3 waves (VGPR attr combo PROVEN honored at this size: R6=112).
//  - tile 4 rows x 64 cols, PX=4 -> acc = 9 x float4 = 36 regs.
//  - dy = 3 (grid dyg) x 3 (wave j); grid 8n x 32hb x 2ws x 3dyg = 1536 blocks
//    = 6 blocks/CU -> 18 waves/CU.
//  - f0 + f1 register-prefetched one chunk (CCH=2 channels) ahead; k-loop
//    touches only LDS + regs. Single 3-wave barrier per iter.
//  - LDS: staged f1 halo 6 rows x 18 16B-units (72 cols), unit u placed at
//    phys p = u + (u>>3), row stride 20 units. Quarter-wave read i: u = tx+i,
//    16 CONSECUTIVE units -> each 4-bank group hit exactly 2x (free, m136).
//  - XCD swizzle: XCD x owns image x; dyg innermost -> siblings time-adjacent,
//    f1/f0 re-reads served by per-XCD L2 (working set ~128 KB/ch-pair << 4MB).

#define DD    9
#define Hh    128
#define Ww    128
#define Cc    256
#define ROWF  80         // physical floats per LDS row (20 units)
#define CBF   480        // floats per channel block (6 rows)
#define BUFF  960        // floats per buffer (2 channels)
#define NCH   128        // chunks of 2 channels

__device__ __forceinline__ int skewu(int u) { return u + (u >> 3); }

__global__ __launch_bounds__(192) __attribute__((amdgpu_waves_per_eu(2, 8)))
void corr_kernel(const float* __restrict__ f0,
                 const float* __restrict__ f1,
                 float* __restrict__ out) {
    const int tid = threadIdx.x;
    const int j   = tid >> 6;          // wave: dy offset 0..2
    const int ty  = (tid >> 4) & 3;    // output row within tile 0..3
    const int tx  = tid & 15;          // col group (4 px) 0..15

    // XCD swizzle: 1536 blocks = 8 XCDs x 192 works; XCD x -> image x.
    const int bid  = blockIdx.x;
    const int n    = bid & 7;
    const int rem  = bid >> 3;         // 0..191
    const int hb   = rem / 6;          // 0..31
    const int r6   = rem % 6;
    const int ws   = r6 / 3;           // 0..1
    const int dyg  = r6 % 3;
    const int dy   = dyg * 3 + j;

    const int h0 = hb * 4;
    const int w0 = ws * 64;

    __shared__ float lds[2 * BUFF];    // 7680 B

    const size_t plane = (size_t)Hh * Ww;
    const float* f0p = f0 + ((size_t)n * Cc) * plane + (size_t)(h0 + ty) * Ww + w0 + 4 * tx;
    const float* f1n = f1 + ((size_t)n * Cc) * plane;

    // ---- staging map: 216 quads per channel-pair chunk (2ch x 6rows x 18u)
    // thread t stages quad q0 = t; threads t<24 also stage q1 = t+192.
    const int q0  = tid;
    const int ch0 = q0 / 108;
    const int rq0 = (q0 % 108) / 18;
    const int u0  = q0 % 18;
    const bool has1 = (tid < 24);
    const int q1  = tid + 192;         // 192..215 -> ch=1, rows 4..5
    const int rq1 = (q1 - 108) / 18;
    const int u1  = q1 % 18;

    const int gh0 = h0 + dyg * 3 - 4 + rq0;
    const int gw0 = w0 + 4 * u0 - 4;
    const int gh1 = h0 + dyg * 3 - 4 + rq1;
    const int gw1 = w0 + 4 * u1 - 4;
    const bool ok0 = ((unsigned)gh0 < (unsigned)Hh) && ((unsigned)gw0 < (unsigned)Ww);
    const bool ok1 = has1 && ((unsigned)gh1 < (unsigned)Hh) && ((unsigned)gw1 < (unsigned)Ww);
    const float* sp0 = f1n + (size_t)ch0 * plane + (size_t)gh0 * Ww + gw0;  // +2*plane/iter
    const float* sp1 = f1n + plane + (size_t)gh1 * Ww + gw1;                // ch1
    const int so0 = ch0 * CBF + rq0 * ROWF + 4 * skewu(u0);
    const int so1 = CBF + rq1 * ROWF + 4 * skewu(u1);

    // ---- read geometry (hoisted)
    const int rbase = (ty + j) * ROWF;
    const int ro0 = rbase + 4 * skewu(tx + 0);
    const int ro1 = rbase + 4 * skewu(tx + 1);
    const int ro2 = rbase + 4 * skewu(tx + 2);

    const float4 zero4 = make_float4(0.f, 0.f, 0.f, 0.f);

    float4 acc[DD];
#pragma unroll
    for (int d = 0; d < DD; ++d) acc[d] = zero4;

    float4 s0, s1;           // f1 staging regs (chunk being written next)
    float4 a0, a1;           // f0 current chunk (2 channels)
    float4 na0, na1;         // f0 next chunk

#define LOADF1(K)                                                        \
    {                                                                    \
        const size_t cofs = (size_t)(2 * (K)) * plane;                   \
        s0 = ok0 ? *(const float4*)(sp0 + cofs) : zero4;                 \
        s1 = ok1 ? *(const float4*)(sp1 + cofs) : zero4;                 \
    }

#define LOADF0(K, d0, d1)                                                \
    {                                                                    \
        const float* p = f0p + (size_t)(2 * (K)) * plane;                \
        d0 = *(const float4*)(p);                                        \
        d1 = *(const float4*)(p + plane);                                \
    }

#define STOREF1(B)                                                       \
    {                                                                    \
        *(float4*)(&lds[(B) * BUFF + so0]) = s0;                         \
        if (has1) *(float4*)(&lds[(B) * BUFF + so1]) = s1;               \
    }

#define COMPUTE(B)                                                       \
    {                                                                    \
        _Pragma("unroll")                                                \
        for (int cc = 0; cc < 2; ++cc) {                                 \
            const float* lrow = &lds[(B) * BUFF + cc * CBF];             \
            const float4 v0 = *(const float4*)(lrow + ro0);              \
            const float4 v1 = *(const float4*)(lrow + ro1);              \
            const float4 v2 = *(const float4*)(lrow + ro2);              \
            const float w[12] = {v0.x, v0.y, v0.z, v0.w,                 \
                                 v1.x, v1.y, v1.z, v1.w,                 \
                                 v2.x, v2.y, v2.z, v2.w};                \
            const float4 a = cc ? a1 : a0;                               \
            _Pragma("unroll")                                            \
            for (int dx = 0; dx < DD; ++dx) {                            \
                acc[dx].x += a.x * w[dx + 0];                            \
                acc[dx].y += a.y * w[dx + 1];                            \
                acc[dx].z += a.z * w[dx + 2];                            \
                acc[dx].w += a.w * w[dx + 3];                            \
            }                                                            \
        }                                                                \
    }

    LOADF1(0);
    LOADF0(0, a0, a1);
    STOREF1(0);
    __syncthreads();

#pragma unroll 2
    for (int k = 0; k < NCH; ++k) {
        const int b = k & 1;
        if (k + 1 < NCH) {
            LOADF1(k + 1);
            LOADF0(k + 1, na0, na1);
        }
        COMPUTE(b);
        if (k + 1 < NCH) {
            STOREF1(b ^ 1);            // buffer nobody reads this iteration
            a0 = na0; a1 = na1;
            __syncthreads();           // single 3-wave barrier per iteration
        }
    }

    // ---- epilogue: 9 quad stores
    float* outp = out + ((size_t)n * (DD * DD) + (size_t)dy * DD) * plane
                      + (size_t)(h0 + ty) * Ww + w0 + 4 * tx;
#pragma unroll
    for (int dx = 0; dx < DD; ++dx)
        *(float4*)(outp + (size_t)dx * plane) = acc[dx];
}

extern "C" void kernel_launch(void* const* d_in, const int* in_sizes, int n_in,
                              void* d_out, int out_size, void* d_ws, size_t ws_size,
                              hipStream_t stream) {
    const float* f0 = (const float*)d_in[0];
    const float* f1 = (const float*)d_in[1];
    float* out = (float*)d_out;
    // grid: 8 n * 32 hb * 2 ws * 3 dyg = 1536 blocks, 192 threads
    corr_kernel<<<dim3(1536), dim3(192), 0, stream>>>(f0, f1, out);
}

// Round 8
// 212.968 us; speedup vs baseline: 1.1038x; 1.0875x over previous
//
#include <hip/hip_runtime.h>

// Correlation / cost volume:
// corr[n, dy*9+dx, h, w] = sum_c f0[n,c,h,w] * f1[n,c,h+dy-4,w+dx-4] (0-padded)
// N=8, C=256, H=W=128 -> D=9, 81 disp channels.
//
// R7 post-mortem: bank conflicts UP (2.95e7; skew breaks at u=8 boundaries for
// i=1,2 reads) and every-iter barrier vmcnt(0) drain exposed f1 load latency
// (COMPUTE ~290cy < L2/L3 ~300-900cy). R8:
//  - LINEAR LDS row = 18 units (72 floats), no skew: any 8-lane cluster has
//    ty fixed + 8 consecutive units -> all 8 bank groups exactly once, both
//    read and write sides. Provably conflict-free.
//  - CCH=4 (64 iters): COMPUTE ~580cy covers the load latency before the
//    barrier's implicit vmcnt(0) drain; half the barriers.
// Kept from R7: 192-thread/3-wave blocks, dy = 3(grid dyg) x 3(wave j),
// tile 4x64 px (PX=4, acc=36 regs), reg-prefetch one chunk ahead, predicated
// OOB->zero staging, XCD swizzle (image per XCD), grid 1536 = 6 blocks/CU.

#define DD    9
#define Hh    128
#define Ww    128
#define Cc    256
#define CCH   4          // channels per chunk
#define NCH   64         // chunks
#define ROWF  72         // floats per LDS row (18 quads, linear)
#define CHF   432        // floats per channel (6 rows)
#define BUFF  1728       // floats per buffer (4 channels)

__global__ __launch_bounds__(192) __attribute__((amdgpu_waves_per_eu(2, 8)))
void corr_kernel(const float* __restrict__ f0,
                 const float* __restrict__ f1,
                 float* __restrict__ out) {
    const int tid = threadIdx.x;
    const int j   = tid >> 6;          // wave: dy offset 0..2
    const int ty  = (tid >> 4) & 3;    // output row within tile 0..3
    const int tx  = tid & 15;          // col group (4 px) 0..15

    const int bid  = blockIdx.x;
    const int n    = bid & 7;          // XCD swizzle: image per XCD
    const int rem  = bid >> 3;         // 0..191
    const int hb   = rem / 6;          // 0..31
    const int r6   = rem % 6;
    const int ws   = r6 / 3;           // 0..1
    const int dyg  = r6 % 3;
    const int dy   = dyg * 3 + j;

    const int h0 = hb * 4;
    const int w0 = ws * 64;

    __shared__ float lds[2 * BUFF];    // 13824 B double-buffered

    const size_t plane = (size_t)Hh * Ww;
    const float* f0p = f0 + ((size_t)n * Cc) * plane + (size_t)(h0 + ty) * Ww + w0 + 4 * tx;
    const float* f1n = f1 + ((size_t)n * Cc) * plane;

    // ---- staging map: 432 quads/chunk (4ch x 6rows x 18u) = 192*2 + 48*1
    const int q0 = tid, q1 = tid + 192, q2 = tid + 384;
    const bool has2 = (tid < 48);

    const int ch0 = q0 / 108, rr0 = (q0 % 108) / 18, u0 = q0 % 18;
    const int ch1 = q1 / 108, rr1 = (q1 % 108) / 18, u1 = q1 % 18;
    const int ch2 = q2 / 108, rr2 = (q2 % 108) / 18, u2 = q2 % 18;

    const int ghb = h0 + dyg * 3 - 4;
    const int gh0 = ghb + rr0, gw0 = w0 + 4 * u0 - 4;
    const int gh1 = ghb + rr1, gw1 = w0 + 4 * u1 - 4;
    const int gh2 = ghb + rr2, gw2 = w0 + 4 * u2 - 4;
    const bool ok0 = ((unsigned)gh0 < (unsigned)Hh) && ((unsigned)gw0 < (unsigned)Ww);
    const bool ok1 = ((unsigned)gh1 < (unsigned)Hh) && ((unsigned)gw1 < (unsigned)Ww);
    const bool ok2 = has2 && ((unsigned)gh2 < (unsigned)Hh) && ((unsigned)gw2 < (unsigned)Ww);
    const float* sp0 = f1n + (size_t)ch0 * plane + (size_t)gh0 * Ww + gw0;
    const float* sp1 = f1n + (size_t)ch1 * plane + (size_t)gh1 * Ww + gw1;
    const float* sp2 = f1n + (size_t)ch2 * plane + (size_t)gh2 * Ww + gw2;
    const int lo0 = ch0 * CHF + rr0 * ROWF + 4 * u0;
    const int lo1 = ch1 * CHF + rr1 * ROWF + 4 * u1;
    const int lo2 = ch2 * CHF + rr2 * ROWF + 4 * u2;

    // ---- read geometry (hoisted): linear row, consecutive units
    const int rbase = (ty + j) * ROWF + 4 * tx;

    const float4 zero4 = make_float4(0.f, 0.f, 0.f, 0.f);

    float4 acc[DD];
#pragma unroll
    for (int d = 0; d < DD; ++d) acc[d] = zero4;

    float4 s0, s1, s2;                 // f1 staging regs
    float4 a0, a1, a2, a3;             // f0 current chunk (4 channels)
    float4 m0, m1, m2, m3;             // f0 next chunk

#define LOADF1(K)                                                        \
    {                                                                    \
        const size_t cofs = (size_t)(CCH * (K)) * plane;                 \
        s0 = ok0 ? *(const float4*)(sp0 + cofs) : zero4;                 \
        s1 = ok1 ? *(const float4*)(sp1 + cofs) : zero4;                 \
        s2 = ok2 ? *(const float4*)(sp2 + cofs) : zero4;                 \
    }

#define LOADF0(K, d0, d1, d2, d3)                                        \
    {                                                                    \
        const float* p = f0p + (size_t)(CCH * (K)) * plane;              \
        d0 = *(const float4*)(p);                                        \
        d1 = *(const float4*)(p + plane);                                \
        d2 = *(const float4*)(p + 2 * plane);                            \
        d3 = *(const float4*)(p + 3 * plane);                            \
    }

#define STOREF1(B)                                                       \
    {                                                                    \
        *(float4*)(&lds[(B) * BUFF + lo0]) = s0;                         \
        *(float4*)(&lds[(B) * BUFF + lo1]) = s1;                         \
        if (has2) *(float4*)(&lds[(B) * BUFF + lo2]) = s2;               \
    }

#define COMP1(B, CC, A)                                                  \
    {                                                                    \
        const float* lrow = &lds[(B) * BUFF + (CC) * CHF + rbase];       \
        const float4 v0 = *(const float4*)(lrow);                        \
        const float4 v1 = *(const float4*)(lrow + 4);                    \
        const float4 v2 = *(const float4*)(lrow + 8);                    \
        const float w[12] = {v0.x, v0.y, v0.z, v0.w,                     \
                             v1.x, v1.y, v1.z, v1.w,                     \
                             v2.x, v2.y, v2.z, v2.w};                    \
        _Pragma("unroll")                                                \
        for (int dx = 0; dx < DD; ++dx) {                                \
            acc[dx].x += (A).x * w[dx + 0];                              \
            acc[dx].y += (A).y * w[dx + 1];                              \
            acc[dx].z += (A).z * w[dx + 2];                              \
            acc[dx].w += (A).w * w[dx + 3];                              \
        }                                                                \
    }

#define COMPUTE(B)                                                       \
    {                                                                    \
        COMP1(B, 0, a0); COMP1(B, 1, a1);                                \
        COMP1(B, 2, a2); COMP1(B, 3, a3);                                \
    }

    LOADF1(0);
    LOADF0(0, a0, a1, a2, a3);
    STOREF1(0);
    __syncthreads();

#pragma unroll 2
    for (int k = 0; k < NCH; ++k) {
        const int b = k & 1;
        if (k + 1 < NCH) {
            LOADF1(k + 1);
            LOADF0(k + 1, m0, m1, m2, m3);
        }
        COMPUTE(b);
        if (k + 1 < NCH) {
            STOREF1(b ^ 1);            // buffer nobody reads this iteration
            a0 = m0; a1 = m1; a2 = m2; a3 = m3;
            __syncthreads();           // 3-wave barrier; loads landed under COMPUTE
        }
    }

    // ---- epilogue: 9 quad stores
    float* outp = out + ((size_t)n * (DD * DD) + (size_t)dy * DD) * plane
                      + (size_t)(h0 + ty) * Ww + w0 + 4 * tx;
#pragma unroll
    for (int dx = 0; dx < DD; ++dx)
        *(float4*)(outp + (size_t)dx * plane) = acc[dx];
}

extern "C" void kernel_launch(void* const* d_in, const int* in_sizes, int n_in,
                              void* d_out, int out_size, void* d_ws, size_t ws_size,
                              hipStream_t stream) {
    const float* f0 = (const float*)d_in[0];
    const float* f1 = (const float*)d_in[1];
    float* out = (float*)d_out;
    // grid: 8 n * 32 hb * 2 ws * 3 dyg = 1536 blocks, 192 threads
    corr_kernel<<<dim3(1536), dim3(192), 0, stream>>>(f0, f1, out);
}